// Round 1
// baseline (68.407 us; speedup 1.0000x reference)
//
#include <hip/hip_runtime.h>
#include <hip/hip_bf16.h>
#include <stdint.h>
#include <math.h>

#define RES     256
#define M_MEAS  8192
#define BATCH   4
#define KDIM    8192        // GEMM reduction length (= M_MEAS)
#define ROWS    2048        // 4 batches * 512 (Re rows 0..255, Im rows 256..511 per batch)
#define COLS    512         // Re Ex cols 0..255, Im Ex cols 256..511
#define SPLIT   8
#define KCHUNK  1024        // KDIM / SPLIT
#define BM      128
#define BN      128
#define BK      32

typedef __attribute__((ext_vector_type(8))) __bf16 bf16x8;
typedef __attribute__((ext_vector_type(8))) unsigned short u16x8;
typedef __attribute__((ext_vector_type(4))) float f32x4;
typedef __attribute__((ext_vector_type(2))) float f32x2;

// ---- workspace layout (bytes) ----
// sRe/sIm : 4*2*8192*4       =   262144
// A  bf16 : 4*512*8192*2     = 33554432   @ 262144
// Bt bf16 : 512*8192*2       =  8388608   @ 33816576
// Cp f32  : 8*2048*512*4     = 33554432   @ 42205184
#define OFF_A  262144
#define OFF_B  33816576
#define OFF_C  42205184

__device__ __forceinline__ unsigned short f2bf(float f) {
    unsigned u = __float_as_uint(f);
    u += 0x7FFFu + ((u >> 16) & 1u);          // round-to-nearest-even
    return (unsigned short)(u >> 16);
}

__device__ __forceinline__ void lds_load16(const void* g, void* l) {
    __builtin_amdgcn_global_load_lds(
        (const __attribute__((address_space(1))) uint32_t*)(uintptr_t)g,
        (__attribute__((address_space(3))) uint32_t*)(uint32_t)(uintptr_t)l,
        16, 0, 0);
}

// ---------------- kernel 1: bilinear gather of complex k-space samples ----------------
__global__ __launch_bounds__(256) void k_gather(const float* __restrict__ in,
                                                const float* __restrict__ xs,
                                                float* __restrict__ sRe,
                                                float* __restrict__ sIm) {
    int t = blockIdx.x * 256 + threadIdx.x;       // 32768
    int b = t >> 13, m = t & (M_MEAS - 1);
    float kx = xs[2 * m + 0], ky = xs[2 * m + 1];
    float gx = (kx * (1.0f / 128.0f) + 1.0f) * 0.5f * 255.0f;
    float gy = (ky * (1.0f / 128.0f) + 1.0f) * 0.5f * 255.0f;
    float fx0 = floorf(gx), fy0 = floorf(gy);
    float wx1 = gx - fx0, wx0 = 1.0f - wx1;
    float wy1 = gy - fy0, wy0 = 1.0f - wy1;
    int x0 = (int)fx0, y0 = (int)fy0;
    float re = 0.0f, im = 0.0f;
#pragma unroll
    for (int dy = 0; dy < 2; ++dy) {
#pragma unroll
        for (int dx = 0; dx < 2; ++dx) {
            int xi = x0 + dx, yi = y0 + dy;
            bool v = (xi >= 0) && (xi < RES) && (yi >= 0) && (yi < RES);
            int xc = min(max(xi, 0), RES - 1);
            int yc = min(max(yi, 0), RES - 1);
            float w = (dx ? wx1 : wx0) * (dy ? wy1 : wy0) * (v ? 1.0f : 0.0f);
            const float* p = in + ((((size_t)b * RES + yc) * RES + xc) * 2);
            re += p[0] * w;
            im += p[1] * w;
        }
    }
    sRe[b * M_MEAS + m] = re;
    sIm[b * M_MEAS + m] = im;
}

// ---------------- kernel 2: build A = [Re(t); Im(t)] per batch, bf16, [2048][8192] ----
__global__ __launch_bounds__(256) void k_buildA(const float* __restrict__ xs,
                                                const float* __restrict__ sRe,
                                                const float* __restrict__ sIm,
                                                unsigned short* __restrict__ A) {
    int t = blockIdx.x * 256 + threadIdx.x;       // 262144
    int y  = t >> 10;                             // 0..255
    int mb = t & 1023;
    int m0 = mb * 8;
    float n = (float)(y - 128);
    float c[8], s_[8];
#pragma unroll
    for (int j = 0; j < 8; ++j) {
        float ky = xs[2 * (m0 + j) + 1];
        float u = ky * n * (1.0f / 256.0f);       // revolutions
        u -= rintf(u);                            // [-0.5, 0.5]
        float th = u * 6.28318530717958647692f;
        s_[j] = __sinf(th);
        c[j]  = __cosf(th);
    }
#pragma unroll
    for (int b = 0; b < BATCH; ++b) {
        u16x8 vr, vi;
#pragma unroll
        for (int j = 0; j < 8; ++j) {
            float sr = sRe[b * M_MEAS + m0 + j];
            float si = sIm[b * M_MEAS + m0 + j];
            vr[j] = f2bf(sr * c[j] - si * s_[j]);
            vi[j] = f2bf(sr * s_[j] + si * c[j]);
        }
        *(u16x8*)(A + ((size_t)b * 512 + y) * KDIM + m0)       = vr;
        *(u16x8*)(A + ((size_t)b * 512 + 256 + y) * KDIM + m0) = vi;
    }
}

// ---------------- kernel 3: build Bt = [Re(Ex); Im(Ex)] bf16, [512][8192] -------------
__global__ __launch_bounds__(256) void k_buildB(const float* __restrict__ xs,
                                                unsigned short* __restrict__ Bt) {
    int t = blockIdx.x * 256 + threadIdx.x;       // 262144
    int xcol = t >> 10;                           // 0..255
    int mb = t & 1023;
    int m0 = mb * 8;
    float n = (float)(xcol - 128);
    u16x8 vc, vs;
#pragma unroll
    for (int j = 0; j < 8; ++j) {
        float kx = xs[2 * (m0 + j) + 0];
        float u = kx * n * (1.0f / 256.0f);
        u -= rintf(u);
        float th = u * 6.28318530717958647692f;
        vs[j] = f2bf(__sinf(th));
        vc[j] = f2bf(__cosf(th));
    }
    *(u16x8*)(Bt + (size_t)xcol * KDIM + m0)         = vc;
    *(u16x8*)(Bt + (size_t)(256 + xcol) * KDIM + m0) = vs;
}

// ---------------- kernel 4: split-K bf16 MFMA GEMM, C = A * Bt^T ----------------------
__global__ __launch_bounds__(256) void k_gemm(const unsigned short* __restrict__ A,
                                              const unsigned short* __restrict__ Bt,
                                              float* __restrict__ Cp) {
    __shared__ __align__(16) unsigned short As[BM * BK];   // 8 KB
    __shared__ __align__(16) unsigned short Bs[BN * BK];   // 8 KB

    int bid   = blockIdx.x;            // 512 = 8 splits * 16 row-tiles * 4 col-tiles
    int split = bid >> 6;
    int tile  = bid & 63;
    int tr = tile >> 2, tc = tile & 3;
    int row0 = tr * BM, col0 = tc * BN;
    int tid = threadIdx.x;
    int w = tid >> 6, l = tid & 63;
    int wr = w >> 1, wc = w & 1;       // 2x2 wave grid, 64x64 out each

    f32x4 acc[4][4] = {};

    int cst = (tid & 3) * 8;           // k-offset within tile this thread stages
    int lr = l & 15, lk = (l >> 4) * 8;

    for (int kt = 0; kt < KCHUNK / BK; ++kt) {
        int k0 = split * KCHUNK + kt * BK;
#pragma unroll
        for (int q = 0; q < 2; ++q) {
            int r = ((q * 256 + tid) >> 2);                 // tile-local row/col
            lds_load16(A  + (size_t)(row0 + r) * KDIM + k0 + cst,
                       As + q * 2048 + w * 512);
            lds_load16(Bt + (size_t)(col0 + r) * KDIM + k0 + cst,
                       Bs + q * 2048 + w * 512);
        }
        __syncthreads();                 // drains vmcnt before ds_read

        bf16x8 af[4], bfr[4];
#pragma unroll
        for (int i = 0; i < 4; ++i) {
            af[i]  = *(const bf16x8*)(As + (wr * 64 + i * 16 + lr) * BK + lk);
            bfr[i] = *(const bf16x8*)(Bs + (wc * 64 + i * 16 + lr) * BK + lk);
        }
#pragma unroll
        for (int i = 0; i < 4; ++i)
#pragma unroll
            for (int j = 0; j < 4; ++j)
                acc[i][j] = __builtin_amdgcn_mfma_f32_16x16x32_bf16(af[i], bfr[j], acc[i][j], 0, 0, 0);
        __syncthreads();                 // protect LDS before next stage
    }

    float* Cb = Cp + (size_t)split * ROWS * COLS;
#pragma unroll
    for (int i = 0; i < 4; ++i) {
#pragma unroll
        for (int j = 0; j < 4; ++j) {
            int colg = col0 + wc * 64 + j * 16 + (l & 15);
#pragma unroll
            for (int v = 0; v < 4; ++v) {
                int rowg = row0 + wr * 64 + i * 16 + (l >> 4) * 4 + v;
                Cb[(size_t)rowg * COLS + colg] = acc[i][j][v];
            }
        }
    }
}

// ---------------- kernel 5: split-K reduce + complex recombination -------------------
__global__ __launch_bounds__(256) void k_combine(const float* __restrict__ Cp,
                                                 float* __restrict__ out) {
    int t = blockIdx.x * 256 + threadIdx.x;       // 262144 = 4*256*256
    int x = t & 255, y = (t >> 8) & 255, b = t >> 16;
    size_t rRe = (size_t)b * 512 + y;
    size_t rIm = rRe + 256;
    float re = 0.0f, im = 0.0f;
#pragma unroll
    for (int s2 = 0; s2 < SPLIT; ++s2) {
        const float* Cb = Cp + (size_t)s2 * ROWS * COLS;
        float c00 = Cb[rRe * COLS + x];            // Re_t * Re_Ex
        float c01 = Cb[rRe * COLS + 256 + x];      // Re_t * Im_Ex
        float c10 = Cb[rIm * COLS + x];            // Im_t * Re_Ex
        float c11 = Cb[rIm * COLS + 256 + x];      // Im_t * Im_Ex
        re += c00 - c11;
        im += c01 + c10;
    }
    ((f32x2*)out)[t] = (f32x2){re, im};
}

extern "C" void kernel_launch(void* const* d_in, const int* in_sizes, int n_in,
                              void* d_out, int out_size, void* d_ws, size_t ws_size,
                              hipStream_t stream) {
    const float* in = (const float*)d_in[0];
    const float* xs = (const float*)d_in[1];
    float* out = (float*)d_out;
    char* ws = (char*)d_ws;

    float* sRe = (float*)ws;
    float* sIm = sRe + BATCH * M_MEAS;
    unsigned short* A  = (unsigned short*)(ws + OFF_A);
    unsigned short* Bt = (unsigned short*)(ws + OFF_B);
    float* Cp = (float*)(ws + OFF_C);

    k_gather <<<128,  256, 0, stream>>>(in, xs, sRe, sIm);
    k_buildA <<<1024, 256, 0, stream>>>(xs, sRe, sIm, A);
    k_buildB <<<1024, 256, 0, stream>>>(xs, Bt);
    k_gemm   <<<512,  256, 0, stream>>>(A, Bt, Cp);
    k_combine<<<1024, 256, 0, stream>>>(Cp, out);
}

// Round 3
// 50.093 us; speedup vs baseline: 1.3656x; 1.3656x over previous
//
#include <hip/hip_runtime.h>
#include <hip/hip_bf16.h>
#include <stdint.h>
#include <math.h>

#define RES     256
#define M_MEAS  8192
#define BATCH   4
#define KDIM    8192
#define ROWS    2048        // 4 batches * {Re 0..255, Im 256..511}
#define NCOLS   288         // deduped: cos u=0..128 at [0,129), sin u=0..128 at [144,273), rest zero-pad
#define SINOFF  144
#define SPLIT   16
#define KCHUNK  512         // KDIM / SPLIT
#define BM      128
#define BN      96
#define BK      32
#define NT      (KCHUNK / BK)   // 16

typedef __attribute__((ext_vector_type(8))) __bf16 bf16x8;
typedef __attribute__((ext_vector_type(8))) unsigned short u16x8;
typedef __attribute__((ext_vector_type(4))) float f32x4;
typedef __attribute__((ext_vector_type(2))) float f32x2;

// ---- workspace layout (bytes) ----
// sRe/sIm : 2*32768*4        =   262144
// A  bf16 : 2048*8192*2      = 33554432   @ 262144
// Bt bf16 : 288*8192*2       =  4718592   @ 33816576
// Cp f32  : 16*2048*288*4    = 37748736   @ 38535168   (total ~76.3 MB)
#define OFF_A  262144
#define OFF_B  33816576
#define OFF_C  38535168

__device__ __forceinline__ unsigned short f2bf(float f) {
    unsigned u = __float_as_uint(f);
    u += 0x7FFFu + ((u >> 16) & 1u);          // round-to-nearest-even
    return (unsigned short)(u >> 16);
}

__device__ __forceinline__ void lds_load16(const void* g, void* l) {
    __builtin_amdgcn_global_load_lds(
        (const __attribute__((address_space(1))) uint32_t*)(uintptr_t)g,
        (__attribute__((address_space(3))) uint32_t*)(uint32_t)(uintptr_t)l,
        16, 0, 0);
}

// ---------------- kernel 1: bilinear gather of complex k-space samples ----------------
__global__ __launch_bounds__(256) void k_gather(const float* __restrict__ in,
                                                const float* __restrict__ xs,
                                                float* __restrict__ sRe,
                                                float* __restrict__ sIm) {
    int t = blockIdx.x * 256 + threadIdx.x;       // 32768
    int b = t >> 13, m = t & (M_MEAS - 1);
    float kx = xs[2 * m + 0], ky = xs[2 * m + 1];
    float gx = (kx * (1.0f / 128.0f) + 1.0f) * 0.5f * 255.0f;
    float gy = (ky * (1.0f / 128.0f) + 1.0f) * 0.5f * 255.0f;
    float fx0 = floorf(gx), fy0 = floorf(gy);
    float wx1 = gx - fx0, wx0 = 1.0f - wx1;
    float wy1 = gy - fy0, wy0 = 1.0f - wy1;
    int x0 = (int)fx0, y0 = (int)fy0;
    float re = 0.0f, im = 0.0f;
#pragma unroll
    for (int dy = 0; dy < 2; ++dy) {
#pragma unroll
        for (int dx = 0; dx < 2; ++dx) {
            int xi = x0 + dx, yi = y0 + dy;
            bool v = (xi >= 0) && (xi < RES) && (yi >= 0) && (yi < RES);
            int xc = min(max(xi, 0), RES - 1);
            int yc = min(max(yi, 0), RES - 1);
            float w = (dx ? wx1 : wx0) * (dy ? wy1 : wy0) * (v ? 1.0f : 0.0f);
            const float* p = in + ((((size_t)b * RES + yc) * RES + xc) * 2);
            re += p[0] * w;
            im += p[1] * w;
        }
    }
    sRe[b * M_MEAS + m] = re;
    sIm[b * M_MEAS + m] = im;
}

// ---------------- kernel 2: build A (t = s*Ey) and deduped Bt (Ex cos/sin) -----------
__global__ __launch_bounds__(256) void k_buildAB(const float* __restrict__ xs,
                                                 const float* __restrict__ sRe,
                                                 const float* __restrict__ sIm,
                                                 unsigned short* __restrict__ A,
                                                 unsigned short* __restrict__ Bt) {
    int blk = blockIdx.x;
    if (blk < 1024) {
        // ---- A part: rows (b, {Re,Im}, y), full y range ----
        int t = blk * 256 + threadIdx.x;          // 262144
        int y  = t >> 10;                         // 0..255
        int m0 = (t & 1023) * 8;
        float n = (float)(y - 128);
        float c[8], s_[8];
#pragma unroll
        for (int j = 0; j < 8; ++j) {
            float ky = xs[2 * (m0 + j) + 1];
            float u = ky * n * (1.0f / 256.0f);   // revolutions
            u -= rintf(u);
            float th = u * 6.28318530717958647692f;
            s_[j] = __sinf(th);
            c[j]  = __cosf(th);
        }
#pragma unroll
        for (int b = 0; b < BATCH; ++b) {
            u16x8 vr, vi;
#pragma unroll
            for (int j = 0; j < 8; ++j) {
                float sr = sRe[b * M_MEAS + m0 + j];
                float si = sIm[b * M_MEAS + m0 + j];
                vr[j] = f2bf(sr * c[j] - si * s_[j]);
                vi[j] = f2bf(sr * s_[j] + si * c[j]);
            }
            *(u16x8*)(A + ((size_t)b * 512 + y) * KDIM + m0)       = vr;
            *(u16x8*)(A + ((size_t)b * 512 + 256 + y) * KDIM + m0) = vi;
        }
    } else {
        // ---- B part: 288 rows (GEMM cols): cos u at [0,129), sin u at [144,273) ----
        int t = (blk - 1024) * 256 + threadIdx.x; // 294912 = 288*1024
        int cidx = t >> 10;                       // 0..287
        int m0 = (t & 1023) * 8;
        bool isCos = cidx < SINOFF;
        int u = isCos ? cidx : (cidx - SINOFF);
        u16x8 v;
        if (u > 128) {
            v = (u16x8){0, 0, 0, 0, 0, 0, 0, 0};
        } else {
            float nn = (float)u;
#pragma unroll
            for (int j = 0; j < 8; ++j) {
                float kx = xs[2 * (m0 + j) + 0];
                float ur = kx * nn * (1.0f / 256.0f);
                ur -= rintf(ur);
                float th = ur * 6.28318530717958647692f;
                v[j] = f2bf(isCos ? __cosf(th) : __sinf(th));
            }
        }
        *(u16x8*)(Bt + (size_t)cidx * KDIM + m0) = v;
    }
}

// ---------------- kernel 3: split-K bf16 MFMA GEMM, double-buffered LDS --------------
__global__ __launch_bounds__(256) void k_gemm(const unsigned short* __restrict__ A,
                                              const unsigned short* __restrict__ Bt,
                                              float* __restrict__ Cp) {
    __shared__ __align__(16) unsigned short As[2][BM * BK];   // 2 x 8 KB
    __shared__ __align__(16) unsigned short Bs[2][BN * BK];   // 2 x 6 KB

    int bid   = blockIdx.x;            // 768 = 48 tiles * 16 splits (split inner)
    int tile  = bid >> 4;
    int split = bid & 15;
    int tr = tile / 3, tc = tile - tr * 3;
    int row0 = tr * BM, col0 = tc * BN;
    int kbase = split * KCHUNK;
    int tid = threadIdx.x;
    int w = tid >> 6, l = tid & 63;
    int wr = w >> 1, wc = w & 1;       // 2x2 wave grid: 64x48 out each

    int srow = tid >> 2;               // staging row (per 4-thread group)
    int skoff = (tid & 3) * 8;         // staging k-offset (elements)

    f32x4 acc[4][3] = {};
    int lr = l & 15, lk = (l >> 4) * 8;

#define STAGE(buf, k0)                                                          \
    do {                                                                        \
        lds_load16(A + (size_t)(row0 + srow) * KDIM + (k0) + skoff,             \
                   &As[buf][(size_t)tid * 8]);                                  \
        lds_load16(A + (size_t)(row0 + 64 + srow) * KDIM + (k0) + skoff,        \
                   &As[buf][(size_t)(256 + tid) * 8]);                          \
        lds_load16(Bt + (size_t)(col0 + srow) * KDIM + (k0) + skoff,            \
                   &Bs[buf][(size_t)tid * 8]);                                  \
        if (tid < 128)                                                          \
            lds_load16(Bt + (size_t)(col0 + 64 + srow) * KDIM + (k0) + skoff,   \
                       &Bs[buf][(size_t)(256 + tid) * 8]);                      \
    } while (0)

    STAGE(0, kbase);
    __syncthreads();                   // drains vmcnt(0): buf0 ready

    int cur = 0;
    for (int kt = 0; kt < NT; ++kt) {
        if (kt < NT - 1) STAGE(cur ^ 1, kbase + (kt + 1) * BK);  // prefetch next

        bf16x8 af[4], bfr[3];
#pragma unroll
        for (int i = 0; i < 4; ++i)
            af[i]  = *(const bf16x8*)(&As[cur][(wr * 64 + i * 16 + lr) * BK + lk]);
#pragma unroll
        for (int j = 0; j < 3; ++j)
            bfr[j] = *(const bf16x8*)(&Bs[cur][(wc * 48 + j * 16 + lr) * BK + lk]);
#pragma unroll
        for (int i = 0; i < 4; ++i)
#pragma unroll
            for (int j = 0; j < 3; ++j)
                acc[i][j] = __builtin_amdgcn_mfma_f32_16x16x32_bf16(af[i], bfr[j], acc[i][j], 0, 0, 0);

        __syncthreads();               // drains vmcnt+lgkm: next buf staged, cur safe to overwrite
        cur ^= 1;
    }
#undef STAGE

    float* Cb = Cp + (size_t)split * ROWS * NCOLS;
#pragma unroll
    for (int i = 0; i < 4; ++i) {
#pragma unroll
        for (int j = 0; j < 3; ++j) {
            int colg = col0 + wc * 48 + j * 16 + (l & 15);
#pragma unroll
            for (int v = 0; v < 4; ++v) {
                int rowg = row0 + wr * 64 + i * 16 + (l >> 4) * 4 + v;
                Cb[(size_t)rowg * NCOLS + colg] = acc[i][j][v];
            }
        }
    }
}

// ---------------- kernel 4: split-K reduce + symmetry + complex recombination --------
__global__ __launch_bounds__(256) void k_combine(const float* __restrict__ Cp,
                                                 float* __restrict__ out) {
    int t = blockIdx.x * 256 + threadIdx.x;       // 262144 = 4*256*256
    int x = t & 255, y = (t >> 8) & 255, b = t >> 16;
    int n = x - 128;
    int u = (n < 0) ? -n : n;
    float sg = (n < 0) ? -1.0f : 1.0f;
    size_t rRe = ((size_t)b * 512 + y) * NCOLS;
    size_t rIm = rRe + (size_t)256 * NCOLS;
    float cr = 0.0f, sr = 0.0f, ci = 0.0f, si = 0.0f;
#pragma unroll
    for (int s2 = 0; s2 < SPLIT; ++s2) {
        const float* Cb = Cp + (size_t)s2 * ROWS * NCOLS;
        cr += Cb[rRe + u];
        sr += Cb[rRe + SINOFF + u];
        ci += Cb[rIm + u];
        si += Cb[rIm + SINOFF + u];
    }
    float re = cr - sg * si;
    float im = sg * sr + ci;
    ((f32x2*)out)[t] = (f32x2){re, im};
}

extern "C" void kernel_launch(void* const* d_in, const int* in_sizes, int n_in,
                              void* d_out, int out_size, void* d_ws, size_t ws_size,
                              hipStream_t stream) {
    const float* in = (const float*)d_in[0];
    const float* xs = (const float*)d_in[1];
    float* out = (float*)d_out;
    char* ws = (char*)d_ws;

    float* sRe = (float*)ws;
    float* sIm = sRe + BATCH * M_MEAS;
    unsigned short* A  = (unsigned short*)(ws + OFF_A);
    unsigned short* Bt = (unsigned short*)(ws + OFF_B);
    float* Cp = (float*)(ws + OFF_C);

    k_gather <<<128,         256, 0, stream>>>(in, xs, sRe, sIm);
    k_buildAB<<<1024 + 1152, 256, 0, stream>>>(xs, sRe, sIm, A, Bt);
    k_gemm   <<<768,         256, 0, stream>>>(A, Bt, Cp);
    k_combine<<<1024,        256, 0, stream>>>(Cp, out);
}

// Round 4
// 48.593 us; speedup vs baseline: 1.4077x; 1.0309x over previous
//
#include <hip/hip_runtime.h>
#include <hip/hip_bf16.h>
#include <stdint.h>
#include <math.h>

#define RES     256
#define M_MEAS  8192
#define BATCH   4
#define KDIM    8192
#define ROWS    2048        // 4 batches * {Re 0..255, Im 256..511}
#define NCOLS   288         // deduped: cos u=0..128 at [0,129), sin u=0..128 at [144,273), rest zero-pad
#define SINOFF  144
#define SPLIT   16
#define KCHUNK  512         // KDIM / SPLIT
#define BM      128
#define BN      96
#define BK      64
#define NT      (KCHUNK / BK)   // 8

typedef __attribute__((ext_vector_type(8))) __bf16 bf16x8;
typedef __attribute__((ext_vector_type(8))) unsigned short u16x8;
typedef __attribute__((ext_vector_type(4))) float f32x4;
typedef __attribute__((ext_vector_type(2))) float f32x2;

// ---- workspace layout (bytes) ----
// sRe/sIm : 2*32768*4        =   262144
// A  bf16 : 2048*8192*2      = 33554432   @ 262144
// Bt bf16 : 288*8192*2       =  4718592   @ 33816576
// Cp f32  : 16*2048*288*4    = 37748736   @ 38535168   (total ~76.3 MB)
#define OFF_A  262144
#define OFF_B  33816576
#define OFF_C  38535168

__device__ __forceinline__ unsigned short f2bf(float f) {
    unsigned u = __float_as_uint(f);
    u += 0x7FFFu + ((u >> 16) & 1u);          // round-to-nearest-even
    return (unsigned short)(u >> 16);
}

__device__ __forceinline__ void lds_load16(const void* g, void* l) {
    __builtin_amdgcn_global_load_lds(
        (const __attribute__((address_space(1))) uint32_t*)(uintptr_t)g,
        (__attribute__((address_space(3))) uint32_t*)(uint32_t)(uintptr_t)l,
        16, 0, 0);
}

// ---------------- kernel 1: bilinear gather of complex k-space samples ----------------
__global__ __launch_bounds__(256) void k_gather(const float* __restrict__ in,
                                                const float* __restrict__ xs,
                                                float* __restrict__ sRe,
                                                float* __restrict__ sIm) {
    int t = blockIdx.x * 256 + threadIdx.x;       // 32768
    int b = t >> 13, m = t & (M_MEAS - 1);
    float kx = xs[2 * m + 0], ky = xs[2 * m + 1];
    float gx = (kx * (1.0f / 128.0f) + 1.0f) * 0.5f * 255.0f;
    float gy = (ky * (1.0f / 128.0f) + 1.0f) * 0.5f * 255.0f;
    float fx0 = floorf(gx), fy0 = floorf(gy);
    float wx1 = gx - fx0, wx0 = 1.0f - wx1;
    float wy1 = gy - fy0, wy0 = 1.0f - wy1;
    int x0 = (int)fx0, y0 = (int)fy0;
    float re = 0.0f, im = 0.0f;
#pragma unroll
    for (int dy = 0; dy < 2; ++dy) {
#pragma unroll
        for (int dx = 0; dx < 2; ++dx) {
            int xi = x0 + dx, yi = y0 + dy;
            bool v = (xi >= 0) && (xi < RES) && (yi >= 0) && (yi < RES);
            int xc = min(max(xi, 0), RES - 1);
            int yc = min(max(yi, 0), RES - 1);
            float w = (dx ? wx1 : wx0) * (dy ? wy1 : wy0) * (v ? 1.0f : 0.0f);
            const float* p = in + ((((size_t)b * RES + yc) * RES + xc) * 2);
            re += p[0] * w;
            im += p[1] * w;
        }
    }
    sRe[b * M_MEAS + m] = re;
    sIm[b * M_MEAS + m] = im;
}

// ---------------- kernel 2: build A (t = s*Ey) and deduped Bt (Ex cos/sin) -----------
__global__ __launch_bounds__(256) void k_buildAB(const float* __restrict__ xs,
                                                 const float* __restrict__ sRe,
                                                 const float* __restrict__ sIm,
                                                 unsigned short* __restrict__ A,
                                                 unsigned short* __restrict__ Bt) {
    int blk = blockIdx.x;
    if (blk < 1024) {
        // ---- A part: rows (b, {Re,Im}, y), full y range ----
        int t = blk * 256 + threadIdx.x;          // 262144
        int y  = t >> 10;                         // 0..255
        int m0 = (t & 1023) * 8;
        float n = (float)(y - 128);
        float c[8], s_[8];
#pragma unroll
        for (int j = 0; j < 8; ++j) {
            float ky = xs[2 * (m0 + j) + 1];
            float u = ky * n * (1.0f / 256.0f);   // revolutions
            u -= rintf(u);
            float th = u * 6.28318530717958647692f;
            s_[j] = __sinf(th);
            c[j]  = __cosf(th);
        }
#pragma unroll
        for (int b = 0; b < BATCH; ++b) {
            u16x8 vr, vi;
#pragma unroll
            for (int j = 0; j < 8; ++j) {
                float sr = sRe[b * M_MEAS + m0 + j];
                float si = sIm[b * M_MEAS + m0 + j];
                vr[j] = f2bf(sr * c[j] - si * s_[j]);
                vi[j] = f2bf(sr * s_[j] + si * c[j]);
            }
            *(u16x8*)(A + ((size_t)b * 512 + y) * KDIM + m0)       = vr;
            *(u16x8*)(A + ((size_t)b * 512 + 256 + y) * KDIM + m0) = vi;
        }
    } else {
        // ---- B part: 288 rows (GEMM cols): cos u at [0,129), sin u at [144,273) ----
        int t = (blk - 1024) * 256 + threadIdx.x; // 294912 = 288*1024
        int cidx = t >> 10;                       // 0..287
        int m0 = (t & 1023) * 8;
        bool isCos = cidx < SINOFF;
        int u = isCos ? cidx : (cidx - SINOFF);
        u16x8 v;
        if (u > 128) {
            v = (u16x8){0, 0, 0, 0, 0, 0, 0, 0};
        } else {
            float nn = (float)u;
#pragma unroll
            for (int j = 0; j < 8; ++j) {
                float kx = xs[2 * (m0 + j) + 0];
                float ur = kx * nn * (1.0f / 256.0f);
                ur -= rintf(ur);
                float th = ur * 6.28318530717958647692f;
                v[j] = f2bf(isCos ? __cosf(th) : __sinf(th));
            }
        }
        *(u16x8*)(Bt + (size_t)cidx * KDIM + m0) = v;
    }
}

// ---------------- kernel 3: split-K bf16 MFMA GEMM ------------------------------------
// BK=64, T2 both-sides XOR swizzle (pre-swizzled global source + swizzled ds_read,
// linear global_load_lds dest), 2-deep counted-vmcnt pipeline (T4), raw s_barrier.
__global__ __launch_bounds__(256, 2) void k_gemm(const unsigned short* __restrict__ A,
                                                 const unsigned short* __restrict__ Bt,
                                                 float* __restrict__ Cp) {
    __shared__ __align__(16) unsigned short As[2][BM * BK];   // 2 x 16 KB
    __shared__ __align__(16) unsigned short Bs[2][BN * BK];   // 2 x 12 KB

    int bid   = blockIdx.x;            // 768 = 48 tiles * 16 splits (split inner)
    int tile  = bid >> 4;
    int split = bid & 15;
    int tr = tile / 3, tc = tile - tr * 3;
    int row0 = tr * BM, col0 = tc * BN;
    int kbase = split * KCHUNK;
    int tid = threadIdx.x;
    int w = tid >> 6, l = tid & 63;
    int wr = w >> 1, wc = w & 1;       // 2x2 wave grid: 64x48 out each

    f32x4 acc[4][3] = {};
    int lr = l & 15, lu = l >> 4;      // fragment row-within-16 / 16B-unit

    // Stage one BK=64 tile: A = 1024 16B-units (4 loads/thread), B = 768 (3 loads).
    // LDS unit U holds global unit (row=U>>3, u=(U&7)^(row&7))  [source pre-swizzle].
#define STAGE(buf, k0)                                                            \
    do {                                                                          \
        _Pragma("unroll")                                                         \
        for (int q = 0; q < 4; ++q) {                                             \
            int U = q * 256 + tid;                                                \
            int r = U >> 3, u = U & 7;                                            \
            lds_load16(A + (size_t)(row0 + r) * KDIM + (k0) + ((u ^ (r & 7)) * 8),\
                       &As[buf][(size_t)U * 8]);                                  \
        }                                                                         \
        _Pragma("unroll")                                                         \
        for (int q = 0; q < 3; ++q) {                                             \
            int U = q * 256 + tid;                                                \
            int r = U >> 3, u = U & 7;                                            \
            lds_load16(Bt + (size_t)(col0 + r) * KDIM + (k0) + ((u ^ (r & 7)) * 8),\
                       &Bs[buf][(size_t)U * 8]);                                  \
        }                                                                         \
    } while (0)

    STAGE(0, kbase);
    STAGE(1, kbase + BK);              // 14 loads in flight

#pragma unroll
    for (int t = 0; t < NT; ++t) {
        int cur = t & 1;
        // wait: this tile's stage complete (1 stage = 7 loads may stay in flight)
        if (t < NT - 1) asm volatile("s_waitcnt vmcnt(7)" ::: "memory");
        else            asm volatile("s_waitcnt vmcnt(0)" ::: "memory");
        __builtin_amdgcn_sched_barrier(0);
        __builtin_amdgcn_s_barrier();            // all waves' stage-t loads landed
        __builtin_amdgcn_sched_barrier(0);

        bf16x8 af[2][4], bfr[2][3];
#pragma unroll
        for (int ks = 0; ks < 2; ++ks) {
#pragma unroll
            for (int i = 0; i < 4; ++i) {
                int row = wr * 64 + i * 16 + lr;
                af[ks][i] = *(const bf16x8*)(&As[cur][row * 64 + (((ks << 2) | lu) ^ (row & 7)) * 8]);
            }
#pragma unroll
            for (int j = 0; j < 3; ++j) {
                int row = wc * 48 + j * 16 + lr;
                bfr[ks][j] = *(const bf16x8*)(&Bs[cur][row * 64 + (((ks << 2) | lu) ^ (row & 7)) * 8]);
            }
        }
        __builtin_amdgcn_sched_barrier(0);
        asm volatile("s_waitcnt lgkmcnt(0)" ::: "memory");   // my ds_reads done
        __builtin_amdgcn_sched_barrier(0);
        __builtin_amdgcn_s_barrier();            // all waves done reading buf[cur]
        __builtin_amdgcn_sched_barrier(0);

        if (t < NT - 2) STAGE(cur, kbase + (t + 2) * BK);    // overwrite freed buffer

#pragma unroll
        for (int ks = 0; ks < 2; ++ks)
#pragma unroll
            for (int i = 0; i < 4; ++i)
#pragma unroll
                for (int j = 0; j < 3; ++j)
                    acc[i][j] = __builtin_amdgcn_mfma_f32_16x16x32_bf16(af[ks][i], bfr[ks][j], acc[i][j], 0, 0, 0);
    }
#undef STAGE

    float* Cb = Cp + (size_t)split * ROWS * NCOLS;
#pragma unroll
    for (int i = 0; i < 4; ++i) {
#pragma unroll
        for (int j = 0; j < 3; ++j) {
            int colg = col0 + wc * 48 + j * 16 + (l & 15);
#pragma unroll
            for (int v = 0; v < 4; ++v) {
                int rowg = row0 + wr * 64 + i * 16 + (l >> 4) * 4 + v;
                Cb[(size_t)rowg * NCOLS + colg] = acc[i][j][v];
            }
        }
    }
}

// ---------------- kernel 4: split-K reduce + symmetry + complex recombination --------
__global__ __launch_bounds__(256) void k_combine(const float* __restrict__ Cp,
                                                 float* __restrict__ out) {
    int t = blockIdx.x * 256 + threadIdx.x;       // 262144 = 4*256*256
    int x = t & 255, y = (t >> 8) & 255, b = t >> 16;
    int n = x - 128;
    int u = (n < 0) ? -n : n;
    float sg = (n < 0) ? -1.0f : 1.0f;
    size_t rRe = ((size_t)b * 512 + y) * NCOLS;
    size_t rIm = rRe + (size_t)256 * NCOLS;
    float cr = 0.0f, sr = 0.0f, ci = 0.0f, si = 0.0f;
#pragma unroll
    for (int s2 = 0; s2 < SPLIT; ++s2) {
        const float* Cb = Cp + (size_t)s2 * ROWS * NCOLS;
        cr += Cb[rRe + u];
        sr += Cb[rRe + SINOFF + u];
        ci += Cb[rIm + u];
        si += Cb[rIm + SINOFF + u];
    }
    float re = cr - sg * si;
    float im = sg * sr + ci;
    ((f32x2*)out)[t] = (f32x2){re, im};
}

extern "C" void kernel_launch(void* const* d_in, const int* in_sizes, int n_in,
                              void* d_out, int out_size, void* d_ws, size_t ws_size,
                              hipStream_t stream) {
    const float* in = (const float*)d_in[0];
    const float* xs = (const float*)d_in[1];
    float* out = (float*)d_out;
    char* ws = (char*)d_ws;

    float* sRe = (float*)ws;
    float* sIm = sRe + BATCH * M_MEAS;
    unsigned short* A  = (unsigned short*)(ws + OFF_A);
    unsigned short* Bt = (unsigned short*)(ws + OFF_B);
    float* Cp = (float*)(ws + OFF_C);

    k_gather <<<128,         256, 0, stream>>>(in, xs, sRe, sIm);
    k_buildAB<<<1024 + 1152, 256, 0, stream>>>(xs, sRe, sIm, A, Bt);
    k_gemm   <<<768,         256, 0, stream>>>(A, Bt, Cp);
    k_combine<<<1024,        256, 0, stream>>>(Cp, out);
}

// Round 6
// 41.151 us; speedup vs baseline: 1.6623x; 1.1809x over previous
//
#include <hip/hip_runtime.h>
#include <hip/hip_bf16.h>
#include <stdint.h>
#include <math.h>

#define RES     256
#define M_MEAS  8192
#define KDIM    8192
#define ROWSC   2048        // 4 batches * {Re 0..255, Im 256..511}
#define NCOLS   288         // cos u at [0,129)+pad, sin u at [144,273)+pad
#define SINOFF  144
#define SPLIT   16
#define KCHUNK  512
#define BM      128
#define BN      144
#define BK      64
#define NT      (KCHUNK / BK)   // 8
#define TWO_PI  6.28318530717958647692f

typedef __attribute__((ext_vector_type(8))) __bf16 bf16x8;
typedef __attribute__((ext_vector_type(8))) unsigned short u16x8;
typedef __attribute__((ext_vector_type(4))) float f32x4;
typedef __attribute__((ext_vector_type(2))) float f32x2;

// ---- workspace layout (bytes) ----
// sRe f32[4*8192] @0        (131072)
// sIm f32[4*8192] @131072   (131072)
// kyc f32[8192]   @262144   (32768)
// Bt  bf16[288][8192] @294912   (4718592)
// Cp  bf16[16][2048][288] @5013504 (18874368)  total ~23.9 MB
#define OFF_SRE 0
#define OFF_SIM 131072
#define OFF_KY  262144
#define OFF_B   294912
#define OFF_C   5013504

__device__ __forceinline__ unsigned short f2bf(float f) {
    unsigned u = __float_as_uint(f);
    u += 0x7FFFu + ((u >> 16) & 1u);          // round-to-nearest-even
    return (unsigned short)(u >> 16);
}

__device__ __forceinline__ float bf2f(unsigned short v) {
    unsigned u = ((unsigned)v) << 16;
    return __uint_as_float(u);
}

__device__ __forceinline__ void lds_load16(const void* g, void* l) {
    __builtin_amdgcn_global_load_lds(
        (const __attribute__((address_space(1))) uint32_t*)(uintptr_t)g,
        (__attribute__((address_space(3))) uint32_t*)(uint32_t)(uintptr_t)l,
        16, 0, 0);
}

// ---------------- kernel 1: gather s + extract ky + build deduped Bt -----------------
__global__ __launch_bounds__(256) void k_prep(const float* __restrict__ in,
                                              const float* __restrict__ xs,
                                              float* __restrict__ sRe,
                                              float* __restrict__ sIm,
                                              float* __restrict__ kyc,
                                              unsigned short* __restrict__ Bt) {
    int blk = blockIdx.x;
    if (blk < 128) {
        // ---- bilinear gather of complex k-space samples ----
        int t = blk * 256 + threadIdx.x;          // 32768
        int b = t >> 13, m = t & (M_MEAS - 1);
        float kx = xs[2 * m + 0], ky = xs[2 * m + 1];
        if (t < M_MEAS) kyc[t] = xs[2 * t + 1];
        float gx = (kx * (1.0f / 128.0f) + 1.0f) * 0.5f * 255.0f;
        float gy = (ky * (1.0f / 128.0f) + 1.0f) * 0.5f * 255.0f;
        float fx0 = floorf(gx), fy0 = floorf(gy);
        float wx1 = gx - fx0, wx0 = 1.0f - wx1;
        float wy1 = gy - fy0, wy0 = 1.0f - wy1;
        int x0 = (int)fx0, y0 = (int)fy0;
        float re = 0.0f, im = 0.0f;
#pragma unroll
        for (int dy = 0; dy < 2; ++dy) {
#pragma unroll
            for (int dx = 0; dx < 2; ++dx) {
                int xi = x0 + dx, yi = y0 + dy;
                bool v = (xi >= 0) && (xi < RES) && (yi >= 0) && (yi < RES);
                int xc = min(max(xi, 0), RES - 1);
                int yc = min(max(yi, 0), RES - 1);
                float w = (dx ? wx1 : wx0) * (dy ? wy1 : wy0) * (v ? 1.0f : 0.0f);
                const float* p = in + ((((size_t)b * RES + yc) * RES + xc) * 2);
                re += p[0] * w;
                im += p[1] * w;
            }
        }
        sRe[b * M_MEAS + m] = re;
        sIm[b * M_MEAS + m] = im;
    } else {
        // ---- Bt: 288 rows: cos u at [0,129)+pad0, sin u at [144,273)+pad0 ----
        int t = (blk - 128) * 256 + threadIdx.x;  // 294912 = 288*1024
        int cidx = t >> 10;
        int m0 = (t & 1023) * 8;
        bool isCos = cidx < SINOFF;
        int u = isCos ? cidx : (cidx - SINOFF);
        u16x8 v;
        if (u > 128) {
            v = (u16x8){0, 0, 0, 0, 0, 0, 0, 0};
        } else {
            float nn = (float)u;
#pragma unroll
            for (int j = 0; j < 8; ++j) {
                float kx = xs[2 * (m0 + j) + 0];
                float ur = kx * nn * (1.0f / 256.0f);
                ur -= rintf(ur);
                float th = ur * TWO_PI;
                v[j] = f2bf(isCos ? __cosf(th) : __sinf(th));
            }
        }
        *(u16x8*)(Bt + (size_t)cidx * KDIM + m0) = v;
    }
}

// ---------------- kernel 2: split-K GEMM with on-the-fly A generation -----------------
// A[row=(b,part,y), m] = s*Ey generated per-tile in LDS (no global A at all).
// B staged via global_load_lds with T2 both-sides XOR swizzle. 1 barrier per K-step.
__global__ __launch_bounds__(256, 2) void k_gemm(const float* __restrict__ sReG,
                                                 const float* __restrict__ sImG,
                                                 const float* __restrict__ kyG,
                                                 const unsigned short* __restrict__ Bt,
                                                 unsigned short* __restrict__ Cp) {
    __shared__ __align__(16) unsigned short As[2][BM * BK];   // 2 x 16 KB
    __shared__ __align__(16) unsigned short Bs[2][BN * BK];   // 2 x 18 KB
    __shared__ __align__(16) float sbuf[3 * KCHUNK];          // ky | sRe | sIm, 6 KB

    int bid = blockIdx.x;              // 512 = 2 col * 16 row * 16 split
    int tc = bid & 1, rest = bid >> 1; // bid&1 -> col-tile: each XCD sees one half of Bt
    int tr = rest & 15, split = rest >> 4;
    int col0 = tc * BN;
    int kbase = split * KCHUNK;
    int yhalf = tr & 1, isIm = (tr >> 1) & 1, batch = tr >> 2;
    int tid = threadIdx.x;
    int w = tid >> 6, l = tid & 63;
    int lr = l & 15, lu = l >> 4;

    f32x4 acc[2][9] = {};

    // ---- B staging: 1152 16B-units, 5 uniform loads (wrap-dup), source pre-swizzled
#define STAGE_B(buf, kt)                                                          \
    do {                                                                          \
        _Pragma("unroll")                                                         \
        for (int q = 0; q < 5; ++q) {                                             \
            int U = q * 256 + tid; if (U >= 1152) U -= 1152;                      \
            int r = U >> 3, u = U & 7;                                            \
            lds_load16(Bt + (size_t)(col0 + r) * KDIM + kbase + (kt) * BK         \
                          + ((u ^ (r & 7)) * 8),                                  \
                       &Bs[buf][U * 8]);                                          \
        }                                                                         \
    } while (0)

    // ---- A generation: lane owns m-pair p, 16 y-rows; sincos once + 15 rotations
#define GEN_A(buf, kt)                                                            \
    do {                                                                          \
        int p = tid & 31, g = tid >> 5;                                           \
        int mi = (kt) * BK + p * 2;                                               \
        float2 kyp = *(const float2*)&sbuf[mi];                                   \
        float2 srp = *(const float2*)&sbuf[KCHUNK + mi];                          \
        float2 sip = *(const float2*)&sbuf[2 * KCHUNK + mi];                      \
        float n0 = (float)(yhalf * 128 + g * 16 - 128);                           \
        float c0, s0, c1, s1, cs0, ss0, cs1, ss1;                                 \
        { float u = kyp.x * n0 * (1.0f/256.0f); u -= rintf(u);                    \
          s0 = __sinf(u * TWO_PI); c0 = __cosf(u * TWO_PI); }                     \
        { float u = kyp.x * (1.0f/256.0f); u -= rintf(u);                         \
          ss0 = __sinf(u * TWO_PI); cs0 = __cosf(u * TWO_PI); }                   \
        { float u = kyp.y * n0 * (1.0f/256.0f); u -= rintf(u);                    \
          s1 = __sinf(u * TWO_PI); c1 = __cosf(u * TWO_PI); }                     \
        { float u = kyp.y * (1.0f/256.0f); u -= rintf(u);                         \
          ss1 = __sinf(u * TWO_PI); cs1 = __cosf(u * TWO_PI); }                   \
        _Pragma("unroll")                                                         \
        for (int j = 0; j < 16; ++j) {                                            \
            int r = g * 16 + j;                                                   \
            float v0 = isIm ? fmaf(srp.x, s0, sip.x * c0)                         \
                            : fmaf(srp.x, c0, -(sip.x * s0));                     \
            float v1 = isIm ? fmaf(srp.y, s1, sip.y * c1)                         \
                            : fmaf(srp.y, c1, -(sip.y * s1));                     \
            unsigned pk = (unsigned)f2bf(v0) | ((unsigned)f2bf(v1) << 16);        \
            *(unsigned*)&As[buf][r * 64 + (((p >> 2) ^ (r & 7)) * 8) + (p & 3) * 2] = pk; \
            float nc0 = fmaf(c0, cs0, -(s0 * ss0));                               \
            float ns0 = fmaf(s0, cs0,  (c0 * ss0));                               \
            c0 = nc0; s0 = ns0;                                                   \
            float nc1 = fmaf(c1, cs1, -(s1 * ss1));                               \
            float ns1 = fmaf(s1, cs1,  (c1 * ss1));                               \
            c1 = nc1; s1 = ns1;                                                   \
        }                                                                         \
    } while (0)

    // ---- prologue: preload s-arrays (384 units, 2 wrap-dup loads) + tile 0 ----
#pragma unroll
    for (int q = 0; q < 2; ++q) {
        int V = q * 256 + tid; if (V >= 384) V -= 384;
        int rg = V >> 7, idx = V & 127;
        const float* s = (rg == 0) ? kyG
                       : (rg == 1) ? (sReG + (size_t)batch * M_MEAS)
                                   : (sImG + (size_t)batch * M_MEAS);
        lds_load16(s + kbase + idx * 4, &sbuf[V * 4]);
    }
    STAGE_B(0, 0);                                   // queue: [s:2, B0:5]
    asm volatile("s_waitcnt vmcnt(5)" ::: "memory"); // s-preload drained
    __builtin_amdgcn_s_barrier();                    // sbuf visible to all waves
    GEN_A(0, 0);                                     // VALU covers B0 latency
    asm volatile("s_waitcnt vmcnt(0) lgkmcnt(0)" ::: "memory");
    __builtin_amdgcn_sched_barrier(0);
    __builtin_amdgcn_s_barrier();                    // buf0 fully ready

    for (int t = 0; t < NT; ++t) {
        int cur = t & 1;
        if (t < NT - 1) {
            STAGE_B(cur ^ 1, t + 1);   // async; long issue-to-wait distance
            GEN_A(cur ^ 1, t + 1);     // heavy VALU overlaps loads + other wave's MFMA
        }

        bf16x8 af[2][2], bfr[2][9];
#pragma unroll
        for (int ks = 0; ks < 2; ++ks) {
            int uu = ks * 4 + lu;
#pragma unroll
            for (int i = 0; i < 2; ++i) {
                int r = w * 32 + i * 16 + lr;
                af[ks][i] = *(const bf16x8*)&As[cur][r * 64 + ((uu ^ (r & 7)) * 8)];
            }
#pragma unroll
            for (int j = 0; j < 9; ++j) {
                int r = j * 16 + lr;
                bfr[ks][j] = *(const bf16x8*)&Bs[cur][r * 64 + ((uu ^ (r & 7)) * 8)];
            }
        }
        asm volatile("s_waitcnt lgkmcnt(0)" ::: "memory");   // frags + A-writes done
        __builtin_amdgcn_sched_barrier(0);
        __builtin_amdgcn_s_setprio(1);
#pragma unroll
        for (int ks = 0; ks < 2; ++ks)
#pragma unroll
            for (int i = 0; i < 2; ++i)
#pragma unroll
                for (int j = 0; j < 9; ++j)
                    acc[i][j] = __builtin_amdgcn_mfma_f32_16x16x32_bf16(af[ks][i], bfr[ks][j], acc[i][j], 0, 0, 0);
        __builtin_amdgcn_s_setprio(0);
        asm volatile("s_waitcnt vmcnt(0)" ::: "memory");     // next tile's B landed
        __builtin_amdgcn_sched_barrier(0);
        __builtin_amdgcn_s_barrier();
    }
#undef STAGE_B
#undef GEN_A

    // ---- epilogue: bf16 partials ----
    unsigned short* Cb = Cp + (size_t)split * ROWSC * NCOLS;
#pragma unroll
    for (int i = 0; i < 2; ++i) {
#pragma unroll
        for (int j = 0; j < 9; ++j) {
            int colg = col0 + j * 16 + lr;
#pragma unroll
            for (int v = 0; v < 4; ++v) {
                int rowg = tr * BM + w * 32 + i * 16 + lu * 4 + v;
                Cb[(size_t)rowg * NCOLS + colg] = f2bf(acc[i][j][v]);
            }
        }
    }
}

// ---------------- kernel 3: split-K reduce + symmetry + complex recombination --------
__global__ __launch_bounds__(256) void k_combine(const unsigned short* __restrict__ Cp,
                                                 float* __restrict__ out) {
    int t = blockIdx.x * 256 + threadIdx.x;       // 262144 = 4*256*256
    int x = t & 255, y = (t >> 8) & 255, b = t >> 16;
    int n = x - 128;
    int u = (n < 0) ? -n : n;
    float sg = (n < 0) ? -1.0f : 1.0f;
    size_t rRe = ((size_t)b * 512 + y) * NCOLS;
    size_t rIm = rRe + (size_t)256 * NCOLS;
    float cr = 0.0f, sr = 0.0f, ci = 0.0f, si = 0.0f;
#pragma unroll
    for (int s2 = 0; s2 < SPLIT; ++s2) {
        const unsigned short* Cb = Cp + (size_t)s2 * ROWSC * NCOLS;
        cr += bf2f(Cb[rRe + u]);
        sr += bf2f(Cb[rRe + SINOFF + u]);
        ci += bf2f(Cb[rIm + u]);
        si += bf2f(Cb[rIm + SINOFF + u]);
    }
    float re = cr - sg * si;
    float im = sg * sr + ci;
    ((f32x2*)out)[t] = (f32x2){re, im};
}

extern "C" void kernel_launch(void* const* d_in, const int* in_sizes, int n_in,
                              void* d_out, int out_size, void* d_ws, size_t ws_size,
                              hipStream_t stream) {
    const float* in = (const float*)d_in[0];
    const float* xs = (const float*)d_in[1];
    float* out = (float*)d_out;
    char* ws = (char*)d_ws;

    float* sRe = (float*)(ws + OFF_SRE);
    float* sIm = (float*)(ws + OFF_SIM);
    float* kyc = (float*)(ws + OFF_KY);
    unsigned short* Bt = (unsigned short*)(ws + OFF_B);
    unsigned short* Cp = (unsigned short*)(ws + OFF_C);

    k_prep   <<<128 + 1152, 256, 0, stream>>>(in, xs, sRe, sIm, kyc, Bt);
    k_gemm   <<<512,        256, 0, stream>>>(sRe, sIm, kyc, Bt, Cp);
    k_combine<<<1024,       256, 0, stream>>>(Cp, out);
}